// Round 2
// baseline (395.876 us; speedup 1.0000x reference)
//
#include <hip/hip_runtime.h>
#include <hip/hip_bf16.h>
#include <math.h>

// MultiSimilarityLoss on MI355X.
// x: [n,128] fp32 L2-normalized; t: [n] int32 labels; out: 4 fp32
// (loss, prec, mean_pos_sim(last row), mean_neg_sim(last row)).
// ep = EPOCH_NUM/300 = 1.0, BASE=0.5, POS_MARGIN=0.9, NEG_MARGIN=0.1.
//
// R17: R16 +
//  (1) neg epilogue barrier-free: row sums reduced via shfl_xor over lq
//      (atomicAdd per row, 2 wx-waves add independently), col sums via
//      shfl_xor over quad bits -> atomicAdd. Removes S4/S5 + pp LDS pass.
//  (2) h1 K-half prefetched global->VGPR during h0 issue (T14 split);
//      ds_write_b128 after S2. h1 global latency folds into S1 drain.
//      Neg tile barriers: 5 -> 3.
//  (3) finalize_kernel fused via threadfence+ticket last-block pattern
//      (counter zeroed in prep). One fewer launch + device drain.
// exp args expanded: neg 50(s-.5)+(.1-s)^2 = s^2+49.8s-24.99
//                    pos -2(s-.5)+(s-.9)^2 = s^2-3.8s+1.81

#define D 128
#define NL 128   // labels are 0..99; padded
#define POSB NL  // pos blocks: one per label group

typedef __attribute__((ext_vector_type(8))) short short8;
typedef __attribute__((ext_vector_type(4))) float float4v;

// ---------------- wave reduce helpers ----------------
__device__ inline float waveSum(float v) {
    #pragma unroll
    for (int o = 32; o > 0; o >>= 1) v += __shfl_down(v, o, 64);
    return v;
}

// async 16B global->LDS (LDS dst: wave-uniform base + lane*16)
__device__ inline void load_lds16(const void* g, void* l) {
    __builtin_amdgcn_global_load_lds(
        (const __attribute__((address_space(1))) unsigned int*)g,
        (__attribute__((address_space(3))) unsigned int*)l, 16, 0, 0);
}

// ---------------- kernel A: convert + bucket + zero workspace ---------------
__global__ __launch_bounds__(1024) void prep_kernel(
    const float* __restrict__ x, ushort* __restrict__ xb, int total8,
    const int* __restrict__ t, int* __restrict__ offs, int* __restrict__ list,
    float* __restrict__ part, float* __restrict__ last4,
    float* __restrict__ out, int* __restrict__ counter, int n, int nconv)
{
    const int tid = threadIdx.x;
    const int bx = blockIdx.x;
    if (bx < nconv) {
        const int g = bx * 1024 + tid;
        if (g >= total8) return;
        const float4* src = (const float4*)(x) + g * 2;
        float4 a = src[0], b = src[1];
        float f[8] = {a.x, a.y, a.z, a.w, b.x, b.y, b.z, b.w};
        ushort r[8];
        #pragma unroll
        for (int i = 0; i < 8; ++i) {
            unsigned u = __float_as_uint(f[i]);
            r[i] = (ushort)((u + 0x7FFFu + ((u >> 16) & 1u)) >> 16);   // RNE
        }
        uint4 packed;
        packed.x = (unsigned)r[0] | ((unsigned)r[1] << 16);
        packed.y = (unsigned)r[2] | ((unsigned)r[3] << 16);
        packed.z = (unsigned)r[4] | ((unsigned)r[5] << 16);
        packed.w = (unsigned)r[6] | ((unsigned)r[7] << 16);
        ((uint4*)xb)[g] = packed;
        return;
    }
    if (bx > nconv) {   // zero part
        const int zb = bx - nconv - 1;
        const int g4 = zb * 4096 + tid * 4;
        if (g4 < 8 * n)
            *(float4*)(part + g4) = (float4){0.f, 0.f, 0.f, 0.f};
        return;
    }
    // bucketing block (also zeroes last4/out accumulators and the ticket)
    __shared__ int cnt[NL], cur[NL];
    if (tid < 4) { last4[tid] = 0.f; out[tid] = 0.f; }
    if (tid == 4) *counter = 0;
    if (tid < NL) cnt[tid] = 0;
    __syncthreads();
    for (int j = tid; j < n; j += 1024) atomicAdd(&cnt[t[j]], 1);
    __syncthreads();
    if (tid == 0) {
        int acc = 0;
        for (int g = 0; g < NL; ++g) { cur[g] = acc; offs[g] = acc; acc += cnt[g]; }
        offs[NL] = acc;
    }
    __syncthreads();
    for (int j = tid; j < n; j += 1024) {
        int p = atomicAdd(&cur[t[j]], 1);
        list[p] = j;
    }
}

// ---------------- kernel B: FUSED pos + neg + last-block finalize ----------
// blocks [0,POSB): pos label groups. blocks [POSB,POSB+ntri): neg tiles.
__global__ __launch_bounds__(256, 3) void fused_kernel(
    const ushort* __restrict__ xb,
    const int* __restrict__ t,
    const int* __restrict__ offs, const int* __restrict__ list,
    float* __restrict__ pos_min, float* __restrict__ pos_sum,
    float* __restrict__ part, float* __restrict__ last4,
    float* __restrict__ out, int* __restrict__ counter, int n)
{
    __shared__ __align__(16) unsigned char smem[32768 + 2048];
    const int tid = threadIdx.x;
    const int bx = blockIdx.x;

    const int w = tid >> 6, lane = tid & 63;
    const int wy = w >> 1, wx = w & 1;
    const int quad = lane >> 4, lq = lane & 15;

    if (bx >= POSB) {
        // ================= NEG tile path =================
        int b = bx - POSB;
        int r = (int)((sqrtf(8.0f * (float)b + 1.0f) - 1.0f) * 0.5f);
        while ((r + 1) * (r + 2) / 2 <= b) ++r;
        while (r * (r + 1) / 2 > b) --r;
        const int c = b - r * (r + 1) / 2;
        const bool offdiag = (r != c);

        const int i0 = r * 128, j0 = c * 128;
        const bool has_last = (i0 == n - 128);

        int* labr = (int*)(smem + 32768);
        int* labc = labr + 128;
        for (int l = tid; l < 128; l += 256) {
            labr[l] = t[i0 + l];
            labc[l] = t[j0 + l];
        }

        uint4* Au = (uint4*)smem;               // [128][8] chunks, swizzled
        uint4* Bu = Au + 128 * 8;
        const uint4* xbv = (const uint4*)xb;
        const short8* As = (const short8*)Au;
        const short8* Bs = (const short8*)Bu;

        // h0 lds-direct stage (K cols [0,64))
        #pragma unroll
        for (int it = 0; it < 4; ++it) {
            const int d = tid + it * 256;       // 0..1023
            const int row = d >> 3;
            const int q = (d & 7) ^ (row & 7);
            const int ub = (d & ~63) * 16;      // wave-uniform byte offset
            load_lds16(xbv + (size_t)(i0 + row) * 16 + q, (char*)Au + ub);
            load_lds16(xbv + (size_t)(j0 + row) * 16 + q, (char*)Bu + ub);
        }
        // h1 register prefetch (K cols [64,128)) — lands during h0 compute
        uint4 pre[8];
        #pragma unroll
        for (int it = 0; it < 4; ++it) {
            const int d = tid + it * 256;
            const int row = d >> 3;
            const int q = (d & 7) ^ (row & 7);
            pre[it * 2]     = xbv[(size_t)(i0 + row) * 16 + 8 + q];
            pre[it * 2 + 1] = xbv[(size_t)(j0 + row) * 16 + 8 + q];
        }

        float4v acc[4][4];
        #pragma unroll
        for (int a = 0; a < 4; ++a)
            #pragma unroll
            for (int d2 = 0; d2 < 4; ++d2) acc[a][d2] = (float4v){0.f, 0.f, 0.f, 0.f};

        __syncthreads();                        // S1: h0 (and pre) landed
        #pragma unroll
        for (int s = 0; s < 2; ++s) {           // h0: k = s*32 + quad*8 + j
            short8 af[4], bf[4];
            #pragma unroll
            for (int tt = 0; tt < 4; ++tt) {
                const int ra = wy * 64 + tt * 16 + lq;
                const int rb2 = wx * 64 + tt * 16 + lq;
                af[tt] = As[ra * 8 + ((s * 4 + quad) ^ (lq & 7))];
                bf[tt] = Bs[rb2 * 8 + ((s * 4 + quad) ^ (lq & 7))];
            }
            #pragma unroll
            for (int tr = 0; tr < 4; ++tr)
                #pragma unroll
                for (int tc = 0; tc < 4; ++tc)
                    acc[tr][tc] = __builtin_amdgcn_mfma_f32_16x16x32_bf16(
                        af[tr], bf[tc], acc[tr][tc], 0, 0, 0);
        }
        __syncthreads();                        // S2: h0 LDS reads done
        #pragma unroll
        for (int it = 0; it < 4; ++it) {        // write h1 from regs
            const int d = tid + it * 256;
            *(uint4*)((char*)Au + d * 16) = pre[it * 2];
            *(uint4*)((char*)Bu + d * 16) = pre[it * 2 + 1];
        }
        __syncthreads();                        // S3: h1 in LDS
        #pragma unroll
        for (int s = 0; s < 2; ++s) {           // h1 compute
            short8 af[4], bf[4];
            #pragma unroll
            for (int tt = 0; tt < 4; ++tt) {
                const int ra = wy * 64 + tt * 16 + lq;
                const int rb2 = wx * 64 + tt * 16 + lq;
                af[tt] = As[ra * 8 + ((s * 4 + quad) ^ (lq & 7))];
                bf[tt] = Bs[rb2 * 8 + ((s * 4 + quad) ^ (lq & 7))];
            }
            #pragma unroll
            for (int tr = 0; tr < 4; ++tr)
                #pragma unroll
                for (int tc = 0; tc < 4; ++tc)
                    acc[tr][tc] = __builtin_amdgcn_mfma_f32_16x16x32_bf16(
                        af[tr], bf[tc], acc[tr][tc], 0, 0, 0);
        }

        // ---------- barrier-free epilogue: shfl reduce + atomics ----------
        int lcv[4];
        #pragma unroll
        for (int tc = 0; tc < 4; ++tc) lcv[tc] = labc[wx * 64 + tc * 16 + lq];
        float colp[4] = {0.f, 0.f, 0.f, 0.f};

        #pragma unroll
        for (int tr = 0; tr < 4; ++tr) {
            #pragma unroll
            for (int reg = 0; reg < 4; ++reg) {
                const int row_loc = wy * 64 + tr * 16 + quad * 4 + reg;
                const int lr = labr[row_loc];
                float ns = 0.f;
                #pragma unroll
                for (int tc = 0; tc < 4; ++tc) {
                    const float s = acc[tr][tc][reg];
                    const bool sel = (lr != lcv[tc]) & (s > 0.1f);
                    const float e = sel
                        ? __expf(fmaf(s, s, fmaf(49.8f, s, -24.99f))) : 0.f;
                    ns += e; colp[tc] += e;
                }

                if (has_last && (i0 + row_loc == n - 1)) {  // last-row stats
                    float ssim = 0.f, ncf = 0.f;
                    #pragma unroll
                    for (int tc = 0; tc < 4; ++tc) {
                        const float s = acc[tr][tc][reg];
                        if ((lr != lcv[tc]) & (s > 0.1f)) { ssim += s; ncf += 1.f; }
                    }
                    #pragma unroll
                    for (int o = 1; o < 16; o <<= 1) {
                        ssim += __shfl_xor(ssim, o, 64);
                        ncf  += __shfl_xor(ncf, o, 64);
                    }
                    if (lq == 0 && ncf > 0.f) {
                        atomicAdd(&last4[2], ssim);
                        atomicAdd(&last4[3], ncf);
                    }
                }

                // reduce this wave's 64-col partial over lq, add to slice
                #pragma unroll
                for (int o = 1; o < 16; o <<= 1) ns += __shfl_xor(ns, o, 64);
                if (lq == 0)
                    atomicAdd(&part[(size_t)(c & 7) * n + i0 + row_loc], ns);
            }
        }
        if (offdiag) {      // transpose contributions: cols of this tile
            #pragma unroll
            for (int tc = 0; tc < 4; ++tc) {
                float v = colp[tc];
                v += __shfl_xor(v, 16, 64);
                v += __shfl_xor(v, 32, 64);     // summed over this wave's 64 rows
                if (lane < 16)
                    atomicAdd(&part[(size_t)(r & 7) * n + j0 + wx * 64 + tc * 16 + lane], v);
            }
        }
    } else {
        // ================= POS group path (MFMA, one block per label) ======
        const int g = bx;
        const int s0 = offs[g], m = offs[g + 1] - s0;
        if (m > 0) {
            uint4* Au = (uint4*)smem;               // [128][8] chunks, swizzled
            uint4* Bu = Au + 128 * 8;
            const uint4* xbv = (const uint4*)xb;
            const short8* As = (const short8*)Au;
            const short8* Bs = (const short8*)Bu;
            int* lrow = (int*)(smem + 33280);       // [128] gathered row ids
            int* lcol = lrow + 128;                 // [128] gathered col ids

            const int lastlab = t[n - 1];
            const bool glast = (g == lastlab);
            const int nrt = (m + 127) >> 7;

            for (int rt = 0; rt < nrt; ++rt) {
                const int rbase = rt << 7;
                const int rleft = min(128, m - rbase);
                for (int ct = 0; ct < nrt; ++ct) {
                    const int cbase = ct << 7;
                    __syncthreads();                // prior pp/lrow readers done
                    for (int l = tid; l < 128; l += 256) {
                        lrow[l] = list[s0 + min(rbase + l, m - 1)];
                        lcol[l] = list[s0 + min(cbase + l, m - 1)];
                    }
                    __syncthreads();

                    float4v acc[4][4];
                    #pragma unroll
                    for (int a = 0; a < 4; ++a)
                        #pragma unroll
                        for (int d2 = 0; d2 < 4; ++d2) acc[a][d2] = (float4v){0.f, 0.f, 0.f, 0.f};

                    #pragma unroll
                    for (int h = 0; h < 2; ++h) {
                        if (h) __syncthreads();
                        #pragma unroll
                        for (int it = 0; it < 4; ++it) {
                            const int d = tid + it * 256;
                            const int row = d >> 3;
                            const int q = (d & 7) ^ (row & 7);
                            const int ub = (d & ~63) * 16;
                            load_lds16(xbv + (size_t)lrow[row] * 16 + h * 8 + q,
                                       (char*)Au + ub);
                            load_lds16(xbv + (size_t)lcol[row] * 16 + h * 8 + q,
                                       (char*)Bu + ub);
                        }
                        __syncthreads();
                        #pragma unroll
                        for (int ks = 0; ks < 2; ++ks) {
                            short8 af[4], bf[4];
                            #pragma unroll
                            for (int tt = 0; tt < 4; ++tt) {
                                const int ra = wy * 64 + tt * 16 + lq;
                                const int rb2 = wx * 64 + tt * 16 + lq;
                                af[tt] = As[ra * 8 + ((ks * 4 + quad) ^ (lq & 7))];
                                bf[tt] = Bs[rb2 * 8 + ((ks * 4 + quad) ^ (lq & 7))];
                            }
                            #pragma unroll
                            for (int tr = 0; tr < 4; ++tr)
                                #pragma unroll
                                for (int tc = 0; tc < 4; ++tc)
                                    acc[tr][tc] = __builtin_amdgcn_mfma_f32_16x16x32_bf16(
                                        af[tr], bf[tc], acc[tr][tc], 0, 0, 0);
                        }
                    }
                    __syncthreads();     // staging reads done -> alias as partials

                    float* pp_s = (float*)smem;                 // [32][129] sum partials
                    float* pp_m = ((float*)smem) + 32 * 129;    // [32][129] min partials
                    float ssl = 0.f, scl = 0.f;
                    bool hadlast = false;

                    #pragma unroll
                    for (int tr = 0; tr < 4; ++tr) {
                        #pragma unroll
                        for (int reg = 0; reg < 4; ++reg) {
                            const int row_loc = wy * 64 + tr * 16 + quad * 4 + reg;
                            float ps = 0.f, mn = INFINITY;
                            #pragma unroll
                            for (int tc = 0; tc < 4; ++tc) {
                                const int col = cbase + wx * 64 + tc * 16 + lq;
                                const float sv = acc[tr][tc][reg];
                                const bool val = (col < m) & (sv < 0.9f);  // excl. self
                                mn = fminf(mn, val ? sv : INFINITY);
                                ps += val ? __expf(fmaf(sv, sv, fmaf(-3.8f, sv, 1.81f))) : 0.f;
                            }
                            pp_s[(wx * 16 + lq) * 129 + row_loc] = ps;
                            pp_m[(wx * 16 + lq) * 129 + row_loc] = mn;

                            if (glast && row_loc < rleft && lrow[row_loc] == n - 1) {
                                hadlast = true;
                                #pragma unroll
                                for (int tc = 0; tc < 4; ++tc) {
                                    const int col = cbase + wx * 64 + tc * 16 + lq;
                                    const float sv = acc[tr][tc][reg];
                                    if ((col < m) & (sv < 0.9f)) { ssl += sv; scl += 1.f; }
                                }
                            }
                        }
                    }
                    if (glast) {
                        #pragma unroll
                        for (int o = 1; o < 16; o <<= 1) {
                            ssl += __shfl_xor(ssl, o, 64);
                            scl += __shfl_xor(scl, o, 64);
                        }
                        if (hadlast && lq == 0) {
                            atomicAdd(&last4[0], ssl);
                            atomicAdd(&last4[1], scl);
                        }
                    }
                    __syncthreads();

                    if (tid < rleft) {
                        float sres = 0.f, mres = INFINITY;
                        #pragma unroll
                        for (int cc = 0; cc < 32; ++cc) {
                            sres += pp_s[cc * 129 + tid];
                            mres = fminf(mres, pp_m[cc * 129 + tid]);
                        }
                        const int i = lrow[tid];
                        if (ct == 0) { pos_sum[i] = sres; pos_min[i] = mres; }
                        else {
                            pos_sum[i] += sres;
                            pos_min[i] = fminf(pos_min[i], mres);
                        }
                    }
                }
            }
        }
    }

    // ================= common tail: ticket; last block finalizes ===========
    __threadfence();                       // release all stores/atomics
    __syncthreads();                       // everyone fenced; LDS quiesced
    int* tkp = (int*)(smem + 16384);
    if (tid == 0) *tkp = atomicAdd(counter, 1);
    __syncthreads();
    if (*tkp != (int)gridDim.x - 1) return;
    __threadfence();                       // acquire side

    // ---------------- finalize (single block, 256 threads) ----------------
    {
        float* xi2f    = (float*)smem;              // [128]
        int*   fl_list = (int*)(smem + 512);        // [2048]
        int*   nflp    = (int*)(smem + 8704);
        float* redS    = (float*)(smem + 8720);     // [12]
        float* lastp   = (float*)(smem + 8768);     // [2]
        float* Lacc    = (float*)(smem + 8776);
        float* Pacc    = (float*)(smem + 8780);
        int*   lastfl  = (int*)(smem + 8784);

        if (tid == 0) { *nflp = 0; *Lacc = 0.f; *Pacc = 0.f; *lastfl = 0; }
        __syncthreads();

        float L = 0.f, P = 0.f;
        for (int i = tid; i < n; i += 256) {
            const float pm = pos_min[i];
            if (pm > 0.6f) {               // pth would exceed 0.1 (incl. +inf)
                int q = atomicAdd(nflp, 1);
                if (q < 2048) fl_list[q] = i;
            } else {
                float s = 0.f;
                #pragma unroll
                for (int sl = 0; sl < 8; ++sl) s += part[(size_t)sl * n + i];
                if (s > 0.f)
                    L += 0.5f * log1pf(pos_sum[i]) + 0.02f * log1pf(s);
                else
                    P += 1.f;
            }
        }
        __syncthreads();
        const int m = min(*nflp, 2048);
        const int wv = tid >> 6;

        for (int e = 0; e < m; ++e) {      // rare: exact recompute of flagged rows
            const int ri = fl_list[e];
            if (tid < D)
                xi2f[tid] = __uint_as_float(((unsigned)xb[(size_t)ri * D + tid]) << 16);
            __syncthreads();
            const float pth = fmaxf(0.1f, pos_min[ri] - 0.5f);
            const int lab = t[ri];
            float S = 0.f, ss = 0.f, cnt = 0.f;
            for (int j = tid; j < n; j += 256) {
                if (t[j] == lab) continue;
                float d = 0.f;
                const ushort* xr = xb + (size_t)j * D;
                for (int q2 = 0; q2 < D; ++q2)
                    d += __uint_as_float(((unsigned)xr[q2]) << 16) * xi2f[q2];
                if (d > pth) {
                    S += __expf(fmaf(d, d, fmaf(49.8f, d, -24.99f)));
                    ss += d; cnt += 1.f;
                }
            }
            S = waveSum(S); ss = waveSum(ss); cnt = waveSum(cnt);
            if (lane == 0) { redS[wv] = S; redS[4 + wv] = ss; redS[8 + wv] = cnt; }
            __syncthreads();
            if (tid == 0) {
                const float Sf = redS[0] + redS[1] + redS[2] + redS[3];
                if (Sf > 0.f)
                    *Lacc += 0.5f * log1pf(pos_sum[ri]) + 0.02f * log1pf(Sf);
                else
                    *Pacc += 1.f;
                if (ri == n - 1) {
                    lastp[0] = redS[4] + redS[5] + redS[6] + redS[7];
                    lastp[1] = redS[8] + redS[9] + redS[10] + redS[11];
                    *lastfl = 1;
                }
            }
            __syncthreads();
        }

        L = waveSum(L); P = waveSum(P);
        if (lane == 0) { redS[wv] = L; redS[4 + wv] = P; }
        __syncthreads();
        if (tid == 0) {
            const float Lt = redS[0] + redS[1] + redS[2] + redS[3] + *Lacc;
            const float Pt = redS[4] + redS[5] + redS[6] + redS[7] + *Pacc;
            out[0] = Lt / (float)n;
            out[1] = Pt / (float)n;
            out[2] = last4[0] / fmaxf(last4[1], 1.f);
            const float a  = (*lastfl) ? lastp[0] : last4[2];
            const float b2 = (*lastfl) ? lastp[1] : last4[3];
            out[3] = a / fmaxf(b2, 1.f);
        }
    }
}

// ---------------- launch ----------------
extern "C" void kernel_launch(void* const* d_in, const int* in_sizes, int n_in,
                              void* d_out, int out_size, void* d_ws, size_t ws_size,
                              hipStream_t stream) {
    const float* x = (const float*)d_in[0];
    const int*   t = (const int*)d_in[1];
    const int n = in_sizes[1];   // 8192

    float* ws      = (float*)d_ws;
    float* pos_min = ws;                       // [n]
    float* pos_sum = ws + n;                   // [n]
    float* last4   = ws + 2 * n;               // [4]   (zeroed by prep)
    float* part    = ws + 2 * n + 4;           // [8*n] (zeroed by prep)
    int*   offs    = (int*)(ws + 10 * n + 4);             // [NL+1]
    int*   list    = (int*)(ws + 10 * n + 4 + NL + 1);    // [n]
    int*   counter = (int*)(ws + 11 * n + 4 + NL + 1);    // [1] ticket
    size_t xb_off  = ((size_t)(11 * n + 4 + NL + 2) + 3) & ~(size_t)3;
    ushort* xb     = (ushort*)(ws + xb_off);              // [n*128] bf16, 16B aligned

    const int total8 = n * D / 8;
    const int nconv = (total8 + 1023) / 1024;
    const int nzero = (8 * n + 4095) / 4096;
    prep_kernel<<<nconv + 1 + nzero, 1024, 0, stream>>>(
        x, xb, total8, t, offs, list, part, last4, (float*)d_out, counter, n, nconv);

    const int nb = n / 128;                    // 64
    const int ntri = nb * (nb + 1) / 2;        // 2080
    fused_kernel<<<POSB + ntri, 256, 0, stream>>>(
        xb, t, offs, list, pos_min, pos_sum, part, last4,
        (float*)d_out, counter, n);
}

// Round 3
// 153.475 us; speedup vs baseline: 2.5794x; 2.5794x over previous
//
#include <hip/hip_runtime.h>
#include <hip/hip_bf16.h>
#include <math.h>

// MultiSimilarityLoss on MI355X.
// x: [n,128] fp32 L2-normalized; t: [n] int32 labels; out: 4 fp32
// (loss, prec, mean_pos_sim(last row), mean_neg_sim(last row)).
// ep = EPOCH_NUM/300 = 1.0, BASE=0.5, POS_MARGIN=0.9, NEG_MARGIN=0.1.
//
// R18: R17 minus the threadfence+ticket finalize fusion (agent-scope
// __threadfence per block forced L2 writeback x2208 blocks -> 82 MB
// WRITE_SIZE, 350 us; worst regression of the session). Back to the
// separate finalize_kernel. KEPT from R17 (both verified, both healthy
// per counters):
//  (1) neg epilogue barrier-free: row sums reduced via shfl_xor over lq,
//      col sums via shfl_xor over lane bits 4/5 -> atomicAdd to part[]
//      (L2-resident, <=8 writer tiles per address). Bank conflicts
//      330K -> 25.6K.
//  (2) h1 K-half prefetched global->VGPR during h0 lds-direct stage
//      (T14 issue-early/write-late); ds_write_b128 after S2. Neg tile
//      barriers: 5 -> 3, h1 global latency hidden under h0 compute.
// exp args expanded: neg 50(s-.5)+(.1-s)^2 = s^2+49.8s-24.99
//                    pos -2(s-.5)+(s-.9)^2 = s^2-3.8s+1.81

#define D 128
#define NL 128   // labels are 0..99; padded
#define POSB NL  // pos blocks: one per label group

typedef __attribute__((ext_vector_type(8))) short short8;
typedef __attribute__((ext_vector_type(4))) float float4v;

// ---------------- wave reduce helpers ----------------
__device__ inline float waveSum(float v) {
    #pragma unroll
    for (int o = 32; o > 0; o >>= 1) v += __shfl_down(v, o, 64);
    return v;
}

// async 16B global->LDS (LDS dst: wave-uniform base + lane*16)
__device__ inline void load_lds16(const void* g, void* l) {
    __builtin_amdgcn_global_load_lds(
        (const __attribute__((address_space(1))) unsigned int*)g,
        (__attribute__((address_space(3))) unsigned int*)l, 16, 0, 0);
}

// ---------------- kernel A: convert + bucket + zero workspace ---------------
__global__ __launch_bounds__(1024) void prep_kernel(
    const float* __restrict__ x, ushort* __restrict__ xb, int total8,
    const int* __restrict__ t, int* __restrict__ offs, int* __restrict__ list,
    float* __restrict__ part, float* __restrict__ last4,
    float* __restrict__ out, int n, int nconv)
{
    const int tid = threadIdx.x;
    const int bx = blockIdx.x;
    if (bx < nconv) {
        const int g = bx * 1024 + tid;
        if (g >= total8) return;
        const float4* src = (const float4*)(x) + g * 2;
        float4 a = src[0], b = src[1];
        float f[8] = {a.x, a.y, a.z, a.w, b.x, b.y, b.z, b.w};
        ushort r[8];
        #pragma unroll
        for (int i = 0; i < 8; ++i) {
            unsigned u = __float_as_uint(f[i]);
            r[i] = (ushort)((u + 0x7FFFu + ((u >> 16) & 1u)) >> 16);   // RNE
        }
        uint4 packed;
        packed.x = (unsigned)r[0] | ((unsigned)r[1] << 16);
        packed.y = (unsigned)r[2] | ((unsigned)r[3] << 16);
        packed.z = (unsigned)r[4] | ((unsigned)r[5] << 16);
        packed.w = (unsigned)r[6] | ((unsigned)r[7] << 16);
        ((uint4*)xb)[g] = packed;
        return;
    }
    if (bx > nconv) {   // zero part
        const int zb = bx - nconv - 1;
        const int g4 = zb * 4096 + tid * 4;
        if (g4 < 8 * n)
            *(float4*)(part + g4) = (float4){0.f, 0.f, 0.f, 0.f};
        return;
    }
    // bucketing block (also zeroes last4 and out accumulators)
    __shared__ int cnt[NL], cur[NL];
    if (tid < 4) { last4[tid] = 0.f; out[tid] = 0.f; }
    if (tid < NL) cnt[tid] = 0;
    __syncthreads();
    for (int j = tid; j < n; j += 1024) atomicAdd(&cnt[t[j]], 1);
    __syncthreads();
    if (tid == 0) {
        int acc = 0;
        for (int g = 0; g < NL; ++g) { cur[g] = acc; offs[g] = acc; acc += cnt[g]; }
        offs[NL] = acc;
    }
    __syncthreads();
    for (int j = tid; j < n; j += 1024) {
        int p = atomicAdd(&cur[t[j]], 1);
        list[p] = j;
    }
}

// ---------------- kernel B: FUSED MFMA pos groups + triangular MFMA neg ----
// blocks [0,POSB): pos label groups. blocks [POSB,POSB+ntri): neg tiles.
__global__ __launch_bounds__(256, 3) void fused_kernel(
    const ushort* __restrict__ xb,
    const int* __restrict__ t,
    const int* __restrict__ offs, const int* __restrict__ list,
    float* __restrict__ pos_min, float* __restrict__ pos_sum,
    float* __restrict__ part, float* __restrict__ last4, int n)
{
    __shared__ __align__(16) unsigned char smem[32768 + 2048];
    const int tid = threadIdx.x;
    const int bx = blockIdx.x;

    const int w = tid >> 6, lane = tid & 63;
    const int wy = w >> 1, wx = w & 1;
    const int quad = lane >> 4, lq = lane & 15;

    if (bx >= POSB) {
        // ================= NEG tile path =================
        int b = bx - POSB;
        int r = (int)((sqrtf(8.0f * (float)b + 1.0f) - 1.0f) * 0.5f);
        while ((r + 1) * (r + 2) / 2 <= b) ++r;
        while (r * (r + 1) / 2 > b) --r;
        const int c = b - r * (r + 1) / 2;
        const bool offdiag = (r != c);

        const int i0 = r * 128, j0 = c * 128;
        const bool has_last = (i0 == n - 128);

        int* labr = (int*)(smem + 32768);
        int* labc = labr + 128;
        for (int l = tid; l < 128; l += 256) {
            labr[l] = t[i0 + l];
            labc[l] = t[j0 + l];
        }

        uint4* Au = (uint4*)smem;               // [128][8] chunks, swizzled
        uint4* Bu = Au + 128 * 8;
        const uint4* xbv = (const uint4*)xb;
        const short8* As = (const short8*)Au;
        const short8* Bs = (const short8*)Bu;

        // h0 lds-direct stage (K cols [0,64))
        #pragma unroll
        for (int it = 0; it < 4; ++it) {
            const int d = tid + it * 256;       // 0..1023
            const int row = d >> 3;
            const int q = (d & 7) ^ (row & 7);
            const int ub = (d & ~63) * 16;      // wave-uniform byte offset
            load_lds16(xbv + (size_t)(i0 + row) * 16 + q, (char*)Au + ub);
            load_lds16(xbv + (size_t)(j0 + row) * 16 + q, (char*)Bu + ub);
        }
        // h1 register prefetch (K cols [64,128)) — lands during h0 compute
        uint4 pre[8];
        #pragma unroll
        for (int it = 0; it < 4; ++it) {
            const int d = tid + it * 256;
            const int row = d >> 3;
            const int q = (d & 7) ^ (row & 7);
            pre[it * 2]     = xbv[(size_t)(i0 + row) * 16 + 8 + q];
            pre[it * 2 + 1] = xbv[(size_t)(j0 + row) * 16 + 8 + q];
        }

        float4v acc[4][4];
        #pragma unroll
        for (int a = 0; a < 4; ++a)
            #pragma unroll
            for (int d2 = 0; d2 < 4; ++d2) acc[a][d2] = (float4v){0.f, 0.f, 0.f, 0.f};

        __syncthreads();                        // S1: h0 (and pre) landed
        #pragma unroll
        for (int s = 0; s < 2; ++s) {           // h0: k = s*32 + quad*8 + j
            short8 af[4], bf[4];
            #pragma unroll
            for (int tt = 0; tt < 4; ++tt) {
                const int ra = wy * 64 + tt * 16 + lq;
                const int rb2 = wx * 64 + tt * 16 + lq;
                af[tt] = As[ra * 8 + ((s * 4 + quad) ^ (lq & 7))];
                bf[tt] = Bs[rb2 * 8 + ((s * 4 + quad) ^ (lq & 7))];
            }
            #pragma unroll
            for (int tr = 0; tr < 4; ++tr)
                #pragma unroll
                for (int tc = 0; tc < 4; ++tc)
                    acc[tr][tc] = __builtin_amdgcn_mfma_f32_16x16x32_bf16(
                        af[tr], bf[tc], acc[tr][tc], 0, 0, 0);
        }
        __syncthreads();                        // S2: h0 LDS reads done
        #pragma unroll
        for (int it = 0; it < 4; ++it) {        // write h1 from regs
            const int d = tid + it * 256;
            *(uint4*)((char*)Au + d * 16) = pre[it * 2];
            *(uint4*)((char*)Bu + d * 16) = pre[it * 2 + 1];
        }
        __syncthreads();                        // S3: h1 in LDS
        #pragma unroll
        for (int s = 0; s < 2; ++s) {           // h1 compute
            short8 af[4], bf[4];
            #pragma unroll
            for (int tt = 0; tt < 4; ++tt) {
                const int ra = wy * 64 + tt * 16 + lq;
                const int rb2 = wx * 64 + tt * 16 + lq;
                af[tt] = As[ra * 8 + ((s * 4 + quad) ^ (lq & 7))];
                bf[tt] = Bs[rb2 * 8 + ((s * 4 + quad) ^ (lq & 7))];
            }
            #pragma unroll
            for (int tr = 0; tr < 4; ++tr)
                #pragma unroll
                for (int tc = 0; tc < 4; ++tc)
                    acc[tr][tc] = __builtin_amdgcn_mfma_f32_16x16x32_bf16(
                        af[tr], bf[tc], acc[tr][tc], 0, 0, 0);
        }

        // ---------- barrier-free epilogue: shfl reduce + atomics ----------
        int lcv[4];
        #pragma unroll
        for (int tc = 0; tc < 4; ++tc) lcv[tc] = labc[wx * 64 + tc * 16 + lq];
        float colp[4] = {0.f, 0.f, 0.f, 0.f};

        #pragma unroll
        for (int tr = 0; tr < 4; ++tr) {
            #pragma unroll
            for (int reg = 0; reg < 4; ++reg) {
                const int row_loc = wy * 64 + tr * 16 + quad * 4 + reg;
                const int lr = labr[row_loc];
                float ns = 0.f;
                #pragma unroll
                for (int tc = 0; tc < 4; ++tc) {
                    const float s = acc[tr][tc][reg];
                    const bool sel = (lr != lcv[tc]) & (s > 0.1f);
                    const float e = sel
                        ? __expf(fmaf(s, s, fmaf(49.8f, s, -24.99f))) : 0.f;
                    ns += e; colp[tc] += e;
                }

                if (has_last && (i0 + row_loc == n - 1)) {  // last-row stats
                    float ssim = 0.f, ncf = 0.f;
                    #pragma unroll
                    for (int tc = 0; tc < 4; ++tc) {
                        const float s = acc[tr][tc][reg];
                        if ((lr != lcv[tc]) & (s > 0.1f)) { ssim += s; ncf += 1.f; }
                    }
                    #pragma unroll
                    for (int o = 1; o < 16; o <<= 1) {
                        ssim += __shfl_xor(ssim, o, 64);
                        ncf  += __shfl_xor(ncf, o, 64);
                    }
                    if (lq == 0 && ncf > 0.f) {
                        atomicAdd(&last4[2], ssim);
                        atomicAdd(&last4[3], ncf);
                    }
                }

                // reduce this wave's 64-col partial over lq, add to slice
                #pragma unroll
                for (int o = 1; o < 16; o <<= 1) ns += __shfl_xor(ns, o, 64);
                if (lq == 0)
                    atomicAdd(&part[(size_t)(c & 7) * n + i0 + row_loc], ns);
            }
        }
        if (offdiag) {      // transpose contributions: cols of this tile
            #pragma unroll
            for (int tc = 0; tc < 4; ++tc) {
                float v = colp[tc];
                v += __shfl_xor(v, 16, 64);
                v += __shfl_xor(v, 32, 64);     // summed over this wave's 64 rows
                if (lane < 16)
                    atomicAdd(&part[(size_t)(r & 7) * n + j0 + wx * 64 + tc * 16 + lane], v);
            }
        }
        return;
    }

    // ================= POS group path (MFMA, one block per label) ==========
    const int g = bx;
    const int s0 = offs[g], m = offs[g + 1] - s0;
    if (m <= 0) return;

    uint4* Au = (uint4*)smem;               // [128][8] chunks, swizzled
    uint4* Bu = Au + 128 * 8;
    const uint4* xbv = (const uint4*)xb;
    const short8* As = (const short8*)Au;
    const short8* Bs = (const short8*)Bu;
    int* lrow = (int*)(smem + 33280);       // [128] gathered row ids
    int* lcol = lrow + 128;                 // [128] gathered col ids
    // pp arrays alias [0,33024) AFTER the MFMA reads are barrier-drained;
    // lrow/lcol live at 33280 so they survive the aliasing.

    const int lastlab = t[n - 1];
    const bool glast = (g == lastlab);
    const int nrt = (m + 127) >> 7;

    for (int rt = 0; rt < nrt; ++rt) {
        const int rbase = rt << 7;
        const int rleft = min(128, m - rbase);
        for (int ct = 0; ct < nrt; ++ct) {
            const int cbase = ct << 7;
            __syncthreads();                // prior pp/lrow readers done
            for (int l = tid; l < 128; l += 256) {
                lrow[l] = list[s0 + min(rbase + l, m - 1)];
                lcol[l] = list[s0 + min(cbase + l, m - 1)];
            }
            __syncthreads();

            float4v acc[4][4];
            #pragma unroll
            for (int a = 0; a < 4; ++a)
                #pragma unroll
                for (int d2 = 0; d2 < 4; ++d2) acc[a][d2] = (float4v){0.f, 0.f, 0.f, 0.f};

            #pragma unroll
            for (int h = 0; h < 2; ++h) {
                if (h) __syncthreads();
                #pragma unroll
                for (int it = 0; it < 4; ++it) {
                    const int d = tid + it * 256;
                    const int row = d >> 3;
                    const int q = (d & 7) ^ (row & 7);
                    const int ub = (d & ~63) * 16;
                    load_lds16(xbv + (size_t)lrow[row] * 16 + h * 8 + q,
                               (char*)Au + ub);
                    load_lds16(xbv + (size_t)lcol[row] * 16 + h * 8 + q,
                               (char*)Bu + ub);
                }
                __syncthreads();
                #pragma unroll
                for (int ks = 0; ks < 2; ++ks) {
                    short8 af[4], bf[4];
                    #pragma unroll
                    for (int tt = 0; tt < 4; ++tt) {
                        const int ra = wy * 64 + tt * 16 + lq;
                        const int rb2 = wx * 64 + tt * 16 + lq;
                        af[tt] = As[ra * 8 + ((ks * 4 + quad) ^ (lq & 7))];
                        bf[tt] = Bs[rb2 * 8 + ((ks * 4 + quad) ^ (lq & 7))];
                    }
                    #pragma unroll
                    for (int tr = 0; tr < 4; ++tr)
                        #pragma unroll
                        for (int tc = 0; tc < 4; ++tc)
                            acc[tr][tc] = __builtin_amdgcn_mfma_f32_16x16x32_bf16(
                                af[tr], bf[tc], acc[tr][tc], 0, 0, 0);
                }
            }
            __syncthreads();     // staging reads done -> alias as partials

            float* pp_s = (float*)smem;                 // [32][129] sum partials
            float* pp_m = ((float*)smem) + 32 * 129;    // [32][129] min partials
            float ssl = 0.f, scl = 0.f;
            bool hadlast = false;

            #pragma unroll
            for (int tr = 0; tr < 4; ++tr) {
                #pragma unroll
                for (int reg = 0; reg < 4; ++reg) {
                    const int row_loc = wy * 64 + tr * 16 + quad * 4 + reg;
                    float ps = 0.f, mn = INFINITY;
                    #pragma unroll
                    for (int tc = 0; tc < 4; ++tc) {
                        const int col = cbase + wx * 64 + tc * 16 + lq;
                        const float sv = acc[tr][tc][reg];
                        const bool val = (col < m) & (sv < 0.9f);  // excl. self
                        mn = fminf(mn, val ? sv : INFINITY);
                        ps += val ? __expf(fmaf(sv, sv, fmaf(-3.8f, sv, 1.81f))) : 0.f;
                    }
                    pp_s[(wx * 16 + lq) * 129 + row_loc] = ps;
                    pp_m[(wx * 16 + lq) * 129 + row_loc] = mn;

                    if (glast && row_loc < rleft && lrow[row_loc] == n - 1) {
                        hadlast = true;
                        #pragma unroll
                        for (int tc = 0; tc < 4; ++tc) {
                            const int col = cbase + wx * 64 + tc * 16 + lq;
                            const float sv = acc[tr][tc][reg];
                            if ((col < m) & (sv < 0.9f)) { ssl += sv; scl += 1.f; }
                        }
                    }
                }
            }
            if (glast) {
                #pragma unroll
                for (int o = 1; o < 16; o <<= 1) {
                    ssl += __shfl_xor(ssl, o, 64);
                    scl += __shfl_xor(scl, o, 64);
                }
                if (hadlast && lq == 0) {
                    atomicAdd(&last4[0], ssl);
                    atomicAdd(&last4[1], scl);
                }
            }
            __syncthreads();

            if (tid < rleft) {
                float sres = 0.f, mres = INFINITY;
                #pragma unroll
                for (int cc = 0; cc < 32; ++cc) {
                    sres += pp_s[cc * 129 + tid];
                    mres = fminf(mres, pp_m[cc * 129 + tid]);
                }
                const int i = lrow[tid];
                if (ct == 0) { pos_sum[i] = sres; pos_min[i] = mres; }
                else {
                    pos_sum[i] += sres;
                    pos_min[i] = fminf(pos_min[i], mres);
                }
            }
        }
    }
}

// ---------------- kernel C: finalize (32 blocks) + exact-path cleanup ------
__global__ __launch_bounds__(256) void finalize_kernel(
    const ushort* __restrict__ xb, const int* __restrict__ t,
    const float* __restrict__ pos_min, const float* __restrict__ pos_sum,
    const float* __restrict__ part, const float* __restrict__ last4,
    float* __restrict__ out, int n)
{
    const int tid = threadIdx.x;
    const int base = blockIdx.x * 256;
    const int i = base + tid;
    const float pm = pos_min[i];
    const bool flag = (pm > 0.6f);   // pth would exceed 0.1 (incl. pm=+inf)

    __shared__ int fl[256];
    __shared__ int nfl, lastflag;
    __shared__ float corr[256];
    __shared__ float xi2[D];
    __shared__ float red[3][4];
    __shared__ float lastst[2];
    if (tid == 0) { nfl = 0; lastflag = 0; }
    __syncthreads();
    if (flag) { int q = atomicAdd(&nfl, 1); fl[q] = tid; }
    __syncthreads();
    const int m = nfl;

    for (int e = 0; e < m; ++e) {    // rare: exact recompute of flagged rows
        const int lr_ = fl[e];
        const int ri = base + lr_;
        if (tid < D)
            xi2[tid] = __uint_as_float(((unsigned)xb[(size_t)ri * D + tid]) << 16);
        __syncthreads();
        const float pth = fmaxf(0.1f, pos_min[ri] - 0.5f);
        const int lab = t[ri];
        float S = 0.f, ss = 0.f, cnt = 0.f;
        for (int j = tid; j < n; j += 256) {
            if (t[j] == lab) continue;
            float d = 0.f;
            const ushort* xr = xb + (size_t)j * D;
            for (int q = 0; q < D; ++q)
                d += __uint_as_float(((unsigned)xr[q]) << 16) * xi2[q];
            if (d > pth) {
                S += __expf(fmaf(d, d, fmaf(49.8f, d, -24.99f)));
                ss += d; cnt += 1.f;
            }
        }
        const int lane = tid & 63, wv = tid >> 6;
        S = waveSum(S); ss = waveSum(ss); cnt = waveSum(cnt);
        if (lane == 0) { red[0][wv] = S; red[1][wv] = ss; red[2][wv] = cnt; }
        __syncthreads();
        if (tid == 0) {
            corr[lr_] = red[0][0] + red[0][1] + red[0][2] + red[0][3];
            if (ri == n - 1) {
                lastst[0] = red[1][0] + red[1][1] + red[1][2] + red[1][3];
                lastst[1] = red[2][0] + red[2][1] + red[2][2] + red[2][3];
                lastflag = 1;
            }
        }
        __syncthreads();
    }

    float s;
    if (flag) {
        s = corr[tid];
    } else {
        s = 0.f;
        #pragma unroll
        for (int sl = 0; sl < 8; ++sl) s += part[(size_t)sl * n + i];
    }
    float l = 0.f, nno = 0.f;
    if (s > 0.f)       // has_neg <=> any exp term (each > 0 in fp32)
        l = 0.5f * log1pf(pos_sum[i]) + 0.02f * log1pf(s);
    else
        nno = 1.f;
    const int lane = tid & 63, wv = tid >> 6;
    l = waveSum(l); nno = waveSum(nno);
    __syncthreads();                  // red[] reuse safety
    if (lane == 0) { red[0][wv] = l; red[1][wv] = nno; }
    __syncthreads();
    if (tid == 0) {
        float L = red[0][0] + red[0][1] + red[0][2] + red[0][3];
        float P = red[1][0] + red[1][1] + red[1][2] + red[1][3];
        atomicAdd(&out[0], L / (float)n);
        atomicAdd(&out[1], P / (float)n);
    }
    if (i == n - 1) {                 // block owning the last row writes stats
        out[2] = last4[0] / fmaxf(last4[1], 1.f);
        float a = lastflag ? lastst[0] : last4[2];
        float b2 = lastflag ? lastst[1] : last4[3];
        out[3] = a / fmaxf(b2, 1.f);
    }
}

// ---------------- launch ----------------
extern "C" void kernel_launch(void* const* d_in, const int* in_sizes, int n_in,
                              void* d_out, int out_size, void* d_ws, size_t ws_size,
                              hipStream_t stream) {
    const float* x = (const float*)d_in[0];
    const int*   t = (const int*)d_in[1];
    const int n = in_sizes[1];   // 8192

    float* ws      = (float*)d_ws;
    float* pos_min = ws;                       // [n]
    float* pos_sum = ws + n;                   // [n]
    float* last4   = ws + 2 * n;               // [4]   (zeroed by prep)
    float* part    = ws + 2 * n + 4;           // [8*n] (zeroed by prep)
    int*   offs    = (int*)(ws + 10 * n + 4);             // [NL+1]
    int*   list    = (int*)(ws + 10 * n + 4 + NL + 1);    // [n]
    size_t xb_off  = ((size_t)(11 * n + 4 + NL + 1) + 3) & ~(size_t)3;
    ushort* xb     = (ushort*)(ws + xb_off);              // [n*128] bf16, 16B aligned

    const int total8 = n * D / 8;
    const int nconv = (total8 + 1023) / 1024;
    const int nzero = (8 * n + 4095) / 4096;
    prep_kernel<<<nconv + 1 + nzero, 1024, 0, stream>>>(
        x, xb, total8, t, offs, list, part, last4, (float*)d_out, n, nconv);

    const int nb = n / 128;                    // 64
    const int ntri = nb * (nb + 1) / 2;        // 2080
    fused_kernel<<<POSB + ntri, 256, 0, stream>>>(
        xb, t, offs, list, pos_min, pos_sum, part, last4, n);

    finalize_kernel<<<n / 256, 256, 0, stream>>>(xb, t, pos_min, pos_sum,
                                                 part, last4, (float*)d_out, n);
}

// Round 5
// 103.887 us; speedup vs baseline: 3.8107x; 1.4773x over previous
//
#include <hip/hip_runtime.h>
#include <hip/hip_bf16.h>
#include <math.h>

// MultiSimilarityLoss on MI355X.
// x: [n,128] fp32 L2-normalized; t: [n] int32 labels; out: 4 fp32
// (loss, prec, mean_pos_sim(last row), mean_neg_sim(last row)).
// ep = EPOCH_NUM/300 = 1.0, BASE=0.5, POS_MARGIN=0.9, NEG_MARGIN=0.1.
//
// R20: R19 + pos-path cross-wave combine fix. R19's register-only pos
// epilogue had wx=0 and wx=1 waves racing non-atomic stores to
// pos_sum/pos_min (each holds only its 64-col half) -> pos_sum halved,
// absmax 0.44. Fix: selected lanes write per-wx totals to a 2KB LDS
// combine area (aliased at head of Au, after a post-MFMA barrier);
// tid<rleft merges both halves and does the single-writer store.
// Neg path unchanged from R19 (single-barrier staging, register-only
// epilogue, atomicAdd merges are race-free).
// exp args expanded: neg 50(s-.5)+(.1-s)^2 = s^2+49.8s-24.99
//                    pos -2(s-.5)+(s-.9)^2 = s^2-3.8s+1.81

#define D 128
#define NL 128   // labels are 0..99; padded
#define POSB NL  // pos blocks: one per label group

typedef __attribute__((ext_vector_type(8))) short short8;
typedef __attribute__((ext_vector_type(4))) float float4v;

// ---------------- wave reduce helpers ----------------
__device__ inline float waveSum(float v) {
    #pragma unroll
    for (int o = 32; o > 0; o >>= 1) v += __shfl_down(v, o, 64);
    return v;
}

// async 16B global->LDS (LDS dst: wave-uniform base + lane*16)
__device__ inline void load_lds16(const void* g, void* l) {
    __builtin_amdgcn_global_load_lds(
        (const __attribute__((address_space(1))) unsigned int*)g,
        (__attribute__((address_space(3))) unsigned int*)l, 16, 0, 0);
}

// ---------------- kernel A: convert + bucket + zero workspace ---------------
__global__ __launch_bounds__(1024) void prep_kernel(
    const float* __restrict__ x, ushort* __restrict__ xb, int total8,
    const int* __restrict__ t, int* __restrict__ offs, int* __restrict__ list,
    float* __restrict__ part, float* __restrict__ last4,
    float* __restrict__ out, int n, int nconv)
{
    const int tid = threadIdx.x;
    const int bx = blockIdx.x;
    if (bx < nconv) {
        const int g = bx * 1024 + tid;
        if (g >= total8) return;
        const float4* src = (const float4*)(x) + g * 2;
        float4 a = src[0], b = src[1];
        float f[8] = {a.x, a.y, a.z, a.w, b.x, b.y, b.z, b.w};
        ushort r[8];
        #pragma unroll
        for (int i = 0; i < 8; ++i) {
            unsigned u = __float_as_uint(f[i]);
            r[i] = (ushort)((u + 0x7FFFu + ((u >> 16) & 1u)) >> 16);   // RNE
        }
        uint4 packed;
        packed.x = (unsigned)r[0] | ((unsigned)r[1] << 16);
        packed.y = (unsigned)r[2] | ((unsigned)r[3] << 16);
        packed.z = (unsigned)r[4] | ((unsigned)r[5] << 16);
        packed.w = (unsigned)r[6] | ((unsigned)r[7] << 16);
        ((uint4*)xb)[g] = packed;
        return;
    }
    if (bx > nconv) {   // zero part
        const int zb = bx - nconv - 1;
        const int g4 = zb * 4096 + tid * 4;
        if (g4 < 8 * n)
            *(float4*)(part + g4) = (float4){0.f, 0.f, 0.f, 0.f};
        return;
    }
    // bucketing block (also zeroes last4 and out accumulators)
    __shared__ int cnt[NL], cur[NL];
    if (tid < 4) { last4[tid] = 0.f; out[tid] = 0.f; }
    if (tid < NL) cnt[tid] = 0;
    __syncthreads();
    for (int j = tid; j < n; j += 1024) atomicAdd(&cnt[t[j]], 1);
    __syncthreads();
    if (tid == 0) {
        int acc = 0;
        for (int g = 0; g < NL; ++g) { cur[g] = acc; offs[g] = acc; acc += cnt[g]; }
        offs[NL] = acc;
    }
    __syncthreads();
    for (int j = tid; j < n; j += 1024) {
        int p = atomicAdd(&cur[t[j]], 1);
        list[p] = j;
    }
}

// ---------------- kernel B: FUSED MFMA pos groups + triangular MFMA neg ----
// blocks [0,POSB): pos label groups. blocks [POSB,POSB+ntri): neg tiles.
__global__ __launch_bounds__(256, 2) void fused_kernel(
    const ushort* __restrict__ xb,
    const int* __restrict__ t,
    const int* __restrict__ offs, const int* __restrict__ list,
    float* __restrict__ pos_min, float* __restrict__ pos_sum,
    float* __restrict__ part, float* __restrict__ last4, int n)
{
    __shared__ __align__(16) unsigned char smem[65536];   // Au|Bu [128][16] u4
    const int tid = threadIdx.x;
    const int bx = blockIdx.x;

    const int w = tid >> 6, lane = tid & 63;
    const int wy = w >> 1, wx = w & 1;
    const int quad = lane >> 4, lq = lane & 15;

    uint4* Au = (uint4*)smem;               // [128][16] chunks, swizzled
    uint4* Bu = Au + 128 * 16;
    const uint4* xbv = (const uint4*)xb;
    const short8* As = (const short8*)Au;
    const short8* Bs = (const short8*)Bu;

    if (bx >= POSB) {
        // ================= NEG tile path (single barrier) =================
        int b = bx - POSB;
        int r = (int)((sqrtf(8.0f * (float)b + 1.0f) - 1.0f) * 0.5f);
        while ((r + 1) * (r + 2) / 2 <= b) ++r;
        while (r * (r + 1) / 2 > b) --r;
        const int c = b - r * (r + 1) / 2;
        const bool offdiag = (r != c);

        const int i0 = r * 128, j0 = c * 128;
        const bool has_last = (i0 == n - 128);

        // stage full rows: 2048 slots/matrix, LDS dst linear, global-side
        // chunk swizzle q = (d&15) ^ (row&7)
        #pragma unroll
        for (int it = 0; it < 8; ++it) {
            const int d = tid + it * 256;   // 0..2047
            const int row = d >> 4;
            const int q = (d & 15) ^ (row & 7);
            const int ub = (d & ~63) * 16;  // wave-uniform byte offset
            load_lds16(xbv + (size_t)(i0 + row) * 16 + q, (char*)Au + ub);
            load_lds16(xbv + (size_t)(j0 + row) * 16 + q, (char*)Bu + ub);
        }

        float4v acc[4][4];
        #pragma unroll
        for (int a = 0; a < 4; ++a)
            #pragma unroll
            for (int d2 = 0; d2 < 4; ++d2) acc[a][d2] = (float4v){0.f, 0.f, 0.f, 0.f};

        __syncthreads();                    // THE barrier: all 64KB landed

        #pragma unroll
        for (int ks = 0; ks < 4; ++ks) {    // k = ks*32 + quad*8 + j
            short8 af[4], bf[4];
            #pragma unroll
            for (int tt = 0; tt < 4; ++tt) {
                const int ra = wy * 64 + tt * 16 + lq;
                const int rb2 = wx * 64 + tt * 16 + lq;
                af[tt] = As[ra * 16 + ((ks * 4 + quad) ^ (lq & 7))];
                bf[tt] = Bs[rb2 * 16 + ((ks * 4 + quad) ^ (lq & 7))];
            }
            #pragma unroll
            for (int tr = 0; tr < 4; ++tr)
                #pragma unroll
                for (int tc = 0; tc < 4; ++tc)
                    acc[tr][tc] = __builtin_amdgcn_mfma_f32_16x16x32_bf16(
                        af[tr], bf[tc], acc[tr][tc], 0, 0, 0);
        }

        // -------- register-only epilogue (no LDS, no barriers) --------
        int lcv[4];
        #pragma unroll
        for (int tc = 0; tc < 4; ++tc) lcv[tc] = t[j0 + wx * 64 + tc * 16 + lq];
        float colp[4] = {0.f, 0.f, 0.f, 0.f};

        #pragma unroll
        for (int tr = 0; tr < 4; ++tr) {
            const int4 lr4 = *(const int4*)&t[i0 + wy * 64 + tr * 16 + quad * 4];
            float ns[4];
            #pragma unroll
            for (int reg = 0; reg < 4; ++reg) {
                const int lr = (reg == 0) ? lr4.x : (reg == 1) ? lr4.y
                             : (reg == 2) ? lr4.z : lr4.w;
                float v = 0.f;
                #pragma unroll
                for (int tc = 0; tc < 4; ++tc) {
                    const float s = acc[tr][tc][reg];
                    const bool sel = (lr != lcv[tc]) & (s > 0.1f);
                    const float e = sel
                        ? __expf(fmaf(s, s, fmaf(49.8f, s, -24.99f))) : 0.f;
                    v += e; colp[tc] += e;
                }
                ns[reg] = v;

                if (has_last && wy == 1 && tr == 3 && quad == 3 && reg == 3) {
                    // row n-1 stats (pth = 0.1)
                    float ssim = 0.f, ncf = 0.f;
                    #pragma unroll
                    for (int tc = 0; tc < 4; ++tc) {
                        const float s = acc[tr][tc][reg];
                        if ((lr != lcv[tc]) & (s > 0.1f)) { ssim += s; ncf += 1.f; }
                    }
                    #pragma unroll
                    for (int o = 1; o < 16; o <<= 1) {
                        ssim += __shfl_xor(ssim, o, 64);
                        ncf  += __shfl_xor(ncf, o, 64);
                    }
                    if (lq == 0 && ncf > 0.f) {
                        atomicAdd(&last4[2], ssim);
                        atomicAdd(&last4[3], ncf);
                    }
                }
            }
            // reduce-scatter over lq: 4-row totals distributed over lq lanes
            const bool b4 = (lq & 4) != 0, b8 = (lq & 8) != 0;
            float s0 = b4 ? ns[0] : ns[2];
            float s1 = b4 ? ns[1] : ns[3];
            float r0 = (b4 ? ns[2] : ns[0]) + __shfl_xor(s0, 4, 64);
            float r1 = (b4 ? ns[3] : ns[1]) + __shfl_xor(s1, 4, 64);
            float s2 = b8 ? r0 : r1;
            float tot = (b8 ? r1 : r0) + __shfl_xor(s2, 8, 64);
            tot += __shfl_xor(tot, 1, 64);
            tot += __shfl_xor(tot, 2, 64);
            if ((lq & 3) == 0) {            // 16 lanes, 16 consecutive rows
                const int rr = quad * 4 + (b4 ? 2 : 0) + (b8 ? 1 : 0);
                atomicAdd(&part[(size_t)(c & 7) * n + i0 + wy * 64 + tr * 16 + rr], tot);
            }
        }
        if (offdiag) {      // transpose contributions: cols of this tile
            #pragma unroll
            for (int tc = 0; tc < 4; ++tc) {
                float v = colp[tc];
                v += __shfl_xor(v, 16, 64);
                v += __shfl_xor(v, 32, 64); // summed over this wave's 64 rows
                if (lane < 16)
                    atomicAdd(&part[(size_t)(r & 7) * n + j0 + wx * 64 + tc * 16 + lane], v);
            }
        }
        return;
    }

    // ================= POS group path (MFMA, one block per label) ==========
    const int g = bx;
    const int s0 = offs[g], m = offs[g + 1] - s0;
    if (m <= 0) return;

    const bool glast = (g == t[n - 1]);
    const int nrt = (m + 127) >> 7;         // almost always 1

    // cross-wave combine area: aliases head of Au AFTER post-MFMA barrier
    float* posS = (float*)smem;             // [2][128]
    float* posM = posS + 256;               // [2][128]

    for (int rt = 0; rt < nrt; ++rt) {
        const int rbase = rt << 7;
        const int rleft = min(128, m - rbase);
        for (int ct = 0; ct < nrt; ++ct) {
            const int cbase = ct << 7;
            if (rt + ct) __syncthreads();   // prior pass LDS readers done

            #pragma unroll
            for (int it = 0; it < 8; ++it) {
                const int d = tid + it * 256;
                const int row = d >> 4;
                const int q = (d & 15) ^ (row & 7);
                const int ub = (d & ~63) * 16;
                const int ia = list[s0 + min(rbase + row, m - 1)];
                const int ib = list[s0 + min(cbase + row, m - 1)];
                load_lds16(xbv + (size_t)ia * 16 + q, (char*)Au + ub);
                load_lds16(xbv + (size_t)ib * 16 + q, (char*)Bu + ub);
            }

            float4v acc[4][4];
            #pragma unroll
            for (int a = 0; a < 4; ++a)
                #pragma unroll
                for (int d2 = 0; d2 < 4; ++d2) acc[a][d2] = (float4v){0.f, 0.f, 0.f, 0.f};

            __syncthreads();                // all 64KB landed

            #pragma unroll
            for (int ks = 0; ks < 4; ++ks) {
                short8 af[4], bf[4];
                #pragma unroll
                for (int tt = 0; tt < 4; ++tt) {
                    const int ra = wy * 64 + tt * 16 + lq;
                    const int rb2 = wx * 64 + tt * 16 + lq;
                    af[tt] = As[ra * 16 + ((ks * 4 + quad) ^ (lq & 7))];
                    bf[tt] = Bs[rb2 * 16 + ((ks * 4 + quad) ^ (lq & 7))];
                }
                #pragma unroll
                for (int tr = 0; tr < 4; ++tr)
                    #pragma unroll
                    for (int tc = 0; tc < 4; ++tc)
                        acc[tr][tc] = __builtin_amdgcn_mfma_f32_16x16x32_bf16(
                            af[tr], bf[tc], acc[tr][tc], 0, 0, 0);
            }
            __syncthreads();                // MFMA LDS reads done -> may alias

            // -------- register epilogue + per-wx LDS combine --------
            float ssl = 0.f, scl = 0.f;
            #pragma unroll
            for (int tr = 0; tr < 4; ++tr) {
                float ps[4], mnv[4];
                #pragma unroll
                for (int reg = 0; reg < 4; ++reg) {
                    const int row_loc = wy * 64 + tr * 16 + quad * 4 + reg;
                    float pv = 0.f, mn = INFINITY;
                    #pragma unroll
                    for (int tc = 0; tc < 4; ++tc) {
                        const int col = cbase + wx * 64 + tc * 16 + lq;
                        const float sv = acc[tr][tc][reg];
                        const bool val = (col < m) & (sv < 0.9f);  // excl. self
                        mn = fminf(mn, val ? sv : INFINITY);
                        pv += val ? __expf(fmaf(sv, sv, fmaf(-3.8f, sv, 1.81f))) : 0.f;
                    }
                    ps[reg] = pv; mnv[reg] = mn;

                    if (glast && row_loc < rleft &&
                        list[s0 + rbase + row_loc] == n - 1) {
                        #pragma unroll
                        for (int tc = 0; tc < 4; ++tc) {
                            const int col = cbase + wx * 64 + tc * 16 + lq;
                            const float sv = acc[tr][tc][reg];
                            if ((col < m) & (sv < 0.9f)) { ssl += sv; scl += 1.f; }
                        }
                    }
                }
                // reduce-scatter over lq (sum for ps, min for mnv)
                const bool b4 = (lq & 4) != 0, b8 = (lq & 8) != 0;
                float a0 = b4 ? ps[0] : ps[2];
                float a1 = b4 ? ps[1] : ps[3];
                float r0 = (b4 ? ps[2] : ps[0]) + __shfl_xor(a0, 4, 64);
                float r1 = (b4 ? ps[3] : ps[1]) + __shfl_xor(a1, 4, 64);
                float a2 = b8 ? r0 : r1;
                float stot = (b8 ? r1 : r0) + __shfl_xor(a2, 8, 64);
                stot += __shfl_xor(stot, 1, 64);
                stot += __shfl_xor(stot, 2, 64);

                float m0 = b4 ? mnv[0] : mnv[2];
                float m1 = b4 ? mnv[1] : mnv[3];
                float q0 = fminf(b4 ? mnv[2] : mnv[0], __shfl_xor(m0, 4, 64));
                float q1 = fminf(b4 ? mnv[3] : mnv[1], __shfl_xor(m1, 4, 64));
                float m2 = b8 ? q0 : q1;
                float mtot = fminf(b8 ? q1 : q0, __shfl_xor(m2, 8, 64));
                mtot = fminf(mtot, __shfl_xor(mtot, 1, 64));
                mtot = fminf(mtot, __shfl_xor(mtot, 2, 64));

                if ((lq & 3) == 0) {        // one writer per (wx,row)
                    const int rr = quad * 4 + (b4 ? 2 : 0) + (b8 ? 1 : 0);
                    const int row_loc = wy * 64 + tr * 16 + rr;
                    posS[wx * 128 + row_loc] = stot;
                    posM[wx * 128 + row_loc] = mtot;
                }
            }
            if (glast) {
                #pragma unroll
                for (int o = 1; o < 16; o <<= 1) {
                    ssl += __shfl_xor(ssl, o, 64);
                    scl += __shfl_xor(scl, o, 64);
                }
                if (lq == 0 && scl > 0.f) {
                    atomicAdd(&last4[0], ssl);
                    atomicAdd(&last4[1], scl);
                }
            }
            __syncthreads();                // combine area complete

            if (tid < rleft) {              // merge wx halves, single writer
                const float stot = posS[tid] + posS[128 + tid];
                const float mtot = fminf(posM[tid], posM[128 + tid]);
                const int i = list[s0 + rbase + tid];
                if (ct == 0) { pos_sum[i] = stot; pos_min[i] = mtot; }
                else {
                    pos_sum[i] += stot;
                    pos_min[i] = fminf(pos_min[i], mtot);
                }
            }
        }
    }
}

// ---------------- kernel C: finalize (32 blocks) + exact-path cleanup ------
__global__ __launch_bounds__(256) void finalize_kernel(
    const ushort* __restrict__ xb, const int* __restrict__ t,
    const float* __restrict__ pos_min, const float* __restrict__ pos_sum,
    const float* __restrict__ part, const float* __restrict__ last4,
    float* __restrict__ out, int n)
{
    const int tid = threadIdx.x;
    const int base = blockIdx.x * 256;
    const int i = base + tid;
    const float pm = pos_min[i];
    const bool flag = (pm > 0.6f);   // pth would exceed 0.1 (incl. pm=+inf)

    __shared__ int fl[256];
    __shared__ int nfl, lastflag;
    __shared__ float corr[256];
    __shared__ float xi2[D];
    __shared__ float red[3][4];
    __shared__ float lastst[2];
    if (tid == 0) { nfl = 0; lastflag = 0; }
    __syncthreads();
    if (flag) { int q = atomicAdd(&nfl, 1); fl[q] = tid; }
    __syncthreads();
    const int m = nfl;

    for (int e = 0; e < m; ++e) {    // rare: exact recompute of flagged rows
        const int lr_ = fl[e];
        const int ri = base + lr_;
        if (tid < D)
            xi2[tid] = __uint_as_float(((unsigned)xb[(size_t)ri * D + tid]) << 16);
        __syncthreads();
        const float pth = fmaxf(0.1f, pos_min[ri] - 0.5f);
        const int lab = t[ri];
        float S = 0.f, ss = 0.f, cnt = 0.f;
        for (int j = tid; j < n; j += 256) {
            if (t[j] == lab) continue;
            float d = 0.f;
            const ushort* xr = xb + (size_t)j * D;
            for (int q = 0; q < D; ++q)
                d += __uint_as_float(((unsigned)xr[q]) << 16) * xi2[q];
            if (d > pth) {
                S += __expf(fmaf(d, d, fmaf(49.8f, d, -24.99f)));
                ss += d; cnt += 1.f;
            }
        }
        const int lane = tid & 63, wv = tid >> 6;
        S = waveSum(S); ss = waveSum(ss); cnt = waveSum(cnt);
        if (lane == 0) { red[0][wv] = S; red[1][wv] = ss; red[2][wv] = cnt; }
        __syncthreads();
        if (tid == 0) {
            corr[lr_] = red[0][0] + red[0][1] + red[0][2] + red[0][3];
            if (ri == n - 1) {
                lastst[0] = red[1][0] + red[1][1] + red[1][2] + red[1][3];
                lastst[1] = red[2][0] + red[2][1] + red[2][2] + red[2][3];
                lastflag = 1;
            }
        }
        __syncthreads();
    }

    float s;
    if (flag) {
        s = corr[tid];
    } else {
        s = 0.f;
        #pragma unroll
        for (int sl = 0; sl < 8; ++sl) s += part[(size_t)sl * n + i];
    }
    float l = 0.f, nno = 0.f;
    if (s > 0.f)       // has_neg <=> any exp term (each > 0 in fp32)
        l = 0.5f * log1pf(pos_sum[i]) + 0.02f * log1pf(s);
    else
        nno = 1.f;
    const int lane = tid & 63, wv = tid >> 6;
    l = waveSum(l); nno = waveSum(nno);
    __syncthreads();                  // red[] reuse safety
    if (lane == 0) { red[0][wv] = l; red[1][wv] = nno; }
    __syncthreads();
    if (tid == 0) {
        float L = red[0][0] + red[0][1] + red[0][2] + red[0][3];
        float P = red[1][0] + red[1][1] + red[1][2] + red[1][3];
        atomicAdd(&out[0], L / (float)n);
        atomicAdd(&out[1], P / (float)n);
    }
    if (i == n - 1) {                 // block owning the last row writes stats
        out[2] = last4[0] / fmaxf(last4[1], 1.f);
        float a = lastflag ? lastst[0] : last4[2];
        float b2 = lastflag ? lastst[1] : last4[3];
        out[3] = a / fmaxf(b2, 1.f);
    }
}

// ---------------- launch ----------------
extern "C" void kernel_launch(void* const* d_in, const int* in_sizes, int n_in,
                              void* d_out, int out_size, void* d_ws, size_t ws_size,
                              hipStream_t stream) {
    const float* x = (const float*)d_in[0];
    const int*   t = (const int*)d_in[1];
    const int n = in_sizes[1];   // 8192

    float* ws      = (float*)d_ws;
    float* pos_min = ws;                       // [n]
    float* pos_sum = ws + n;                   // [n]
    float* last4   = ws + 2 * n;               // [4]   (zeroed by prep)
    float* part    = ws + 2 * n + 4;           // [8*n] (zeroed by prep)
    int*   offs    = (int*)(ws + 10 * n + 4);             // [NL+1]
    int*   list    = (int*)(ws + 10 * n + 4 + NL + 1);    // [n]
    size_t xb_off  = ((size_t)(11 * n + 4 + NL + 1) + 3) & ~(size_t)3;
    ushort* xb     = (ushort*)(ws + xb_off);              // [n*128] bf16, 16B aligned

    const int total8 = n * D / 8;
    const int nconv = (total8 + 1023) / 1024;
    const int nzero = (8 * n + 4095) / 4096;
    prep_kernel<<<nconv + 1 + nzero, 1024, 0, stream>>>(
        x, xb, total8, t, offs, list, part, last4, (float*)d_out, n, nconv);

    const int nb = n / 128;                    // 64
    const int ntri = nb * (nb + 1) / 2;        // 2080
    fused_kernel<<<POSB + ntri, 256, 0, stream>>>(
        xb, t, offs, list, pos_min, pos_sum, part, last4, n);

    finalize_kernel<<<n / 256, 256, 0, stream>>>(xb, t, pos_min, pos_sum,
                                                 part, last4, (float*)d_out, n);
}

// Round 6
// 97.718 us; speedup vs baseline: 4.0512x; 1.0631x over previous
//
#include <hip/hip_runtime.h>
#include <hip/hip_bf16.h>
#include <math.h>

// MultiSimilarityLoss on MI355X.
// x: [n,128] fp32 L2-normalized; t: [n] int32 labels; out: 4 fp32
// (loss, prec, mean_pos_sim(last row), mean_neg_sim(last row)).
// ep = EPOCH_NUM/300 = 1.0, BASE=0.5, POS_MARGIN=0.9, NEG_MARGIN=0.1.
//
// R21: R20's single-barrier 64KB-LDS tile cost a resident block
// (2 blocks/CU vs 3) and regressed fused ~28.6 -> ~38 us; the barrier
// savings didn't pay for the lost TLP (staging drain + exp epilogue
// need wave overlap). This round: the never-benched clean combo --
//  - 2-half lds-direct staging ([128][8] chunks/half, 32KB LDS total,
//    3 barriers/tile; R16's verified pattern, NO register prefetch),
//  - register-only shfl reduce-scatter epilogues (R19/R20, verified),
//  - pos path keeps R20's posS/posM LDS cross-wave combine (aliases
//    staging buffer after a post-MFMA barrier),
//  - __launch_bounds__(256,3): 3 blocks/CU (LDS allows 5, VGPR ~110
//    live incl. unified AGPRs -> no spill at cap ~170).
// exp args expanded: neg 50(s-.5)+(.1-s)^2 = s^2+49.8s-24.99
//                    pos -2(s-.5)+(s-.9)^2 = s^2-3.8s+1.81

#define D 128
#define NL 128   // labels are 0..99; padded
#define POSB NL  // pos blocks: one per label group

typedef __attribute__((ext_vector_type(8))) short short8;
typedef __attribute__((ext_vector_type(4))) float float4v;

// ---------------- wave reduce helpers ----------------
__device__ inline float waveSum(float v) {
    #pragma unroll
    for (int o = 32; o > 0; o >>= 1) v += __shfl_down(v, o, 64);
    return v;
}

// async 16B global->LDS (LDS dst: wave-uniform base + lane*16)
__device__ inline void load_lds16(const void* g, void* l) {
    __builtin_amdgcn_global_load_lds(
        (const __attribute__((address_space(1))) unsigned int*)g,
        (__attribute__((address_space(3))) unsigned int*)l, 16, 0, 0);
}

// ---------------- kernel A: convert + bucket + zero workspace ---------------
__global__ __launch_bounds__(1024) void prep_kernel(
    const float* __restrict__ x, ushort* __restrict__ xb, int total8,
    const int* __restrict__ t, int* __restrict__ offs, int* __restrict__ list,
    float* __restrict__ part, float* __restrict__ last4,
    float* __restrict__ out, int n, int nconv)
{
    const int tid = threadIdx.x;
    const int bx = blockIdx.x;
    if (bx < nconv) {
        const int g = bx * 1024 + tid;
        if (g >= total8) return;
        const float4* src = (const float4*)(x) + g * 2;
        float4 a = src[0], b = src[1];
        float f[8] = {a.x, a.y, a.z, a.w, b.x, b.y, b.z, b.w};
        ushort r[8];
        #pragma unroll
        for (int i = 0; i < 8; ++i) {
            unsigned u = __float_as_uint(f[i]);
            r[i] = (ushort)((u + 0x7FFFu + ((u >> 16) & 1u)) >> 16);   // RNE
        }
        uint4 packed;
        packed.x = (unsigned)r[0] | ((unsigned)r[1] << 16);
        packed.y = (unsigned)r[2] | ((unsigned)r[3] << 16);
        packed.z = (unsigned)r[4] | ((unsigned)r[5] << 16);
        packed.w = (unsigned)r[6] | ((unsigned)r[7] << 16);
        ((uint4*)xb)[g] = packed;
        return;
    }
    if (bx > nconv) {   // zero part
        const int zb = bx - nconv - 1;
        const int g4 = zb * 4096 + tid * 4;
        if (g4 < 8 * n)
            *(float4*)(part + g4) = (float4){0.f, 0.f, 0.f, 0.f};
        return;
    }
    // bucketing block (also zeroes last4 and out accumulators)
    __shared__ int cnt[NL], cur[NL];
    if (tid < 4) { last4[tid] = 0.f; out[tid] = 0.f; }
    if (tid < NL) cnt[tid] = 0;
    __syncthreads();
    for (int j = tid; j < n; j += 1024) atomicAdd(&cnt[t[j]], 1);
    __syncthreads();
    if (tid == 0) {
        int acc = 0;
        for (int g = 0; g < NL; ++g) { cur[g] = acc; offs[g] = acc; acc += cnt[g]; }
        offs[NL] = acc;
    }
    __syncthreads();
    for (int j = tid; j < n; j += 1024) {
        int p = atomicAdd(&cur[t[j]], 1);
        list[p] = j;
    }
}

// ---------------- kernel B: FUSED MFMA pos groups + triangular MFMA neg ----
// blocks [0,POSB): pos label groups. blocks [POSB,POSB+ntri): neg tiles.
__global__ __launch_bounds__(256, 3) void fused_kernel(
    const ushort* __restrict__ xb,
    const int* __restrict__ t,
    const int* __restrict__ offs, const int* __restrict__ list,
    float* __restrict__ pos_min, float* __restrict__ pos_sum,
    float* __restrict__ part, float* __restrict__ last4, int n)
{
    __shared__ __align__(16) unsigned char smem[32768];   // Au|Bu [128][8] u4
    const int tid = threadIdx.x;
    const int bx = blockIdx.x;

    const int w = tid >> 6, lane = tid & 63;
    const int wy = w >> 1, wx = w & 1;
    const int quad = lane >> 4, lq = lane & 15;

    uint4* Au = (uint4*)smem;               // [128][8] chunks, swizzled
    uint4* Bu = Au + 128 * 8;
    const uint4* xbv = (const uint4*)xb;
    const short8* As = (const short8*)Au;
    const short8* Bs = (const short8*)Bu;

    if (bx >= POSB) {
        // ================= NEG tile path (2-half staging) =================
        int b = bx - POSB;
        int r = (int)((sqrtf(8.0f * (float)b + 1.0f) - 1.0f) * 0.5f);
        while ((r + 1) * (r + 2) / 2 <= b) ++r;
        while (r * (r + 1) / 2 > b) --r;
        const int c = b - r * (r + 1) / 2;
        const bool offdiag = (r != c);

        const int i0 = r * 128, j0 = c * 128;
        const bool has_last = (i0 == n - 128);

        float4v acc[4][4];
        #pragma unroll
        for (int a = 0; a < 4; ++a)
            #pragma unroll
            for (int d2 = 0; d2 < 4; ++d2) acc[a][d2] = (float4v){0.f, 0.f, 0.f, 0.f};

        #pragma unroll
        for (int h = 0; h < 2; ++h) {       // K half: cols [h*64, h*64+64)
            if (h) __syncthreads();         // h0 LDS readers done
            #pragma unroll
            for (int it = 0; it < 4; ++it) {
                const int d = tid + it * 256;   // 0..1023
                const int row = d >> 3;
                const int q = (d & 7) ^ (row & 7);
                const int ub = (d & ~63) * 16;  // wave-uniform byte offset
                load_lds16(xbv + (size_t)(i0 + row) * 16 + h * 8 + q,
                           (char*)Au + ub);
                load_lds16(xbv + (size_t)(j0 + row) * 16 + h * 8 + q,
                           (char*)Bu + ub);
            }
            __syncthreads();                // drains vmcnt (loads landed)
            #pragma unroll
            for (int s = 0; s < 2; ++s) {   // k = h*64 + s*32 + quad*8 + j
                short8 af[4], bf[4];
                #pragma unroll
                for (int tt = 0; tt < 4; ++tt) {
                    const int ra = wy * 64 + tt * 16 + lq;
                    const int rb2 = wx * 64 + tt * 16 + lq;
                    af[tt] = As[ra * 8 + ((s * 4 + quad) ^ (lq & 7))];
                    bf[tt] = Bs[rb2 * 8 + ((s * 4 + quad) ^ (lq & 7))];
                }
                #pragma unroll
                for (int tr = 0; tr < 4; ++tr)
                    #pragma unroll
                    for (int tc = 0; tc < 4; ++tc)
                        acc[tr][tc] = __builtin_amdgcn_mfma_f32_16x16x32_bf16(
                            af[tr], bf[tc], acc[tr][tc], 0, 0, 0);
            }
        }

        // -------- register-only epilogue (no LDS, no barriers) --------
        int lcv[4];
        #pragma unroll
        for (int tc = 0; tc < 4; ++tc) lcv[tc] = t[j0 + wx * 64 + tc * 16 + lq];
        float colp[4] = {0.f, 0.f, 0.f, 0.f};

        #pragma unroll
        for (int tr = 0; tr < 4; ++tr) {
            const int4 lr4 = *(const int4*)&t[i0 + wy * 64 + tr * 16 + quad * 4];
            float ns[4];
            #pragma unroll
            for (int reg = 0; reg < 4; ++reg) {
                const int lr = (reg == 0) ? lr4.x : (reg == 1) ? lr4.y
                             : (reg == 2) ? lr4.z : lr4.w;
                float v = 0.f;
                #pragma unroll
                for (int tc = 0; tc < 4; ++tc) {
                    const float s = acc[tr][tc][reg];
                    const bool sel = (lr != lcv[tc]) & (s > 0.1f);
                    const float e = sel
                        ? __expf(fmaf(s, s, fmaf(49.8f, s, -24.99f))) : 0.f;
                    v += e; colp[tc] += e;
                }
                ns[reg] = v;

                if (has_last && wy == 1 && tr == 3 && quad == 3 && reg == 3) {
                    // row n-1 stats (pth = 0.1)
                    float ssim = 0.f, ncf = 0.f;
                    #pragma unroll
                    for (int tc = 0; tc < 4; ++tc) {
                        const float s = acc[tr][tc][reg];
                        if ((lr != lcv[tc]) & (s > 0.1f)) { ssim += s; ncf += 1.f; }
                    }
                    #pragma unroll
                    for (int o = 1; o < 16; o <<= 1) {
                        ssim += __shfl_xor(ssim, o, 64);
                        ncf  += __shfl_xor(ncf, o, 64);
                    }
                    if (lq == 0 && ncf > 0.f) {
                        atomicAdd(&last4[2], ssim);
                        atomicAdd(&last4[3], ncf);
                    }
                }
            }
            // reduce-scatter over lq: 4-row totals distributed over lq lanes
            const bool b4 = (lq & 4) != 0, b8 = (lq & 8) != 0;
            float s0 = b4 ? ns[0] : ns[2];
            float s1 = b4 ? ns[1] : ns[3];
            float r0 = (b4 ? ns[2] : ns[0]) + __shfl_xor(s0, 4, 64);
            float r1 = (b4 ? ns[3] : ns[1]) + __shfl_xor(s1, 4, 64);
            float s2 = b8 ? r0 : r1;
            float tot = (b8 ? r1 : r0) + __shfl_xor(s2, 8, 64);
            tot += __shfl_xor(tot, 1, 64);
            tot += __shfl_xor(tot, 2, 64);
            if ((lq & 3) == 0) {            // 16 lanes, 16 consecutive rows
                const int rr = quad * 4 + (b4 ? 2 : 0) + (b8 ? 1 : 0);
                atomicAdd(&part[(size_t)(c & 7) * n + i0 + wy * 64 + tr * 16 + rr], tot);
            }
        }
        if (offdiag) {      // transpose contributions: cols of this tile
            #pragma unroll
            for (int tc = 0; tc < 4; ++tc) {
                float v = colp[tc];
                v += __shfl_xor(v, 16, 64);
                v += __shfl_xor(v, 32, 64); // summed over this wave's 64 rows
                if (lane < 16)
                    atomicAdd(&part[(size_t)(r & 7) * n + j0 + wx * 64 + tc * 16 + lane], v);
            }
        }
        return;
    }

    // ================= POS group path (MFMA, one block per label) ==========
    const int g = bx;
    const int s0 = offs[g], m = offs[g + 1] - s0;
    if (m <= 0) return;

    const bool glast = (g == t[n - 1]);
    const int nrt = (m + 127) >> 7;         // almost always 1

    // cross-wave combine area: aliases head of Au AFTER post-MFMA barrier
    float* posS = (float*)smem;             // [2][128]
    float* posM = posS + 256;               // [2][128]

    for (int rt = 0; rt < nrt; ++rt) {
        const int rbase = rt << 7;
        const int rleft = min(128, m - rbase);
        for (int ct = 0; ct < nrt; ++ct) {
            const int cbase = ct << 7;
            if (rt + ct) __syncthreads();   // prior pass LDS readers done

            float4v acc[4][4];
            #pragma unroll
            for (int a = 0; a < 4; ++a)
                #pragma unroll
                for (int d2 = 0; d2 < 4; ++d2) acc[a][d2] = (float4v){0.f, 0.f, 0.f, 0.f};

            #pragma unroll
            for (int h = 0; h < 2; ++h) {
                if (h) __syncthreads();     // h0 LDS readers done
                #pragma unroll
                for (int it = 0; it < 4; ++it) {
                    const int d = tid + it * 256;
                    const int row = d >> 3;
                    const int q = (d & 7) ^ (row & 7);
                    const int ub = (d & ~63) * 16;
                    const int ia = list[s0 + min(rbase + row, m - 1)];
                    const int ib = list[s0 + min(cbase + row, m - 1)];
                    load_lds16(xbv + (size_t)ia * 16 + h * 8 + q,
                               (char*)Au + ub);
                    load_lds16(xbv + (size_t)ib * 16 + h * 8 + q,
                               (char*)Bu + ub);
                }
                __syncthreads();            // drains vmcnt
                #pragma unroll
                for (int ks = 0; ks < 2; ++ks) {
                    short8 af[4], bf[4];
                    #pragma unroll
                    for (int tt = 0; tt < 4; ++tt) {
                        const int ra = wy * 64 + tt * 16 + lq;
                        const int rb2 = wx * 64 + tt * 16 + lq;
                        af[tt] = As[ra * 8 + ((ks * 4 + quad) ^ (lq & 7))];
                        bf[tt] = Bs[rb2 * 8 + ((ks * 4 + quad) ^ (lq & 7))];
                    }
                    #pragma unroll
                    for (int tr = 0; tr < 4; ++tr)
                        #pragma unroll
                        for (int tc = 0; tc < 4; ++tc)
                            acc[tr][tc] = __builtin_amdgcn_mfma_f32_16x16x32_bf16(
                                af[tr], bf[tc], acc[tr][tc], 0, 0, 0);
                }
            }
            __syncthreads();                // MFMA LDS reads done -> may alias

            // -------- register epilogue + per-wx LDS combine --------
            float ssl = 0.f, scl = 0.f;
            #pragma unroll
            for (int tr = 0; tr < 4; ++tr) {
                float ps[4], mnv[4];
                #pragma unroll
                for (int reg = 0; reg < 4; ++reg) {
                    const int row_loc = wy * 64 + tr * 16 + quad * 4 + reg;
                    float pv = 0.f, mn = INFINITY;
                    #pragma unroll
                    for (int tc = 0; tc < 4; ++tc) {
                        const int col = cbase + wx * 64 + tc * 16 + lq;
                        const float sv = acc[tr][tc][reg];
                        const bool val = (col < m) & (sv < 0.9f);  // excl. self
                        mn = fminf(mn, val ? sv : INFINITY);
                        pv += val ? __expf(fmaf(sv, sv, fmaf(-3.8f, sv, 1.81f))) : 0.f;
                    }
                    ps[reg] = pv; mnv[reg] = mn;

                    if (glast && row_loc < rleft &&
                        list[s0 + rbase + row_loc] == n - 1) {
                        #pragma unroll
                        for (int tc = 0; tc < 4; ++tc) {
                            const int col = cbase + wx * 64 + tc * 16 + lq;
                            const float sv = acc[tr][tc][reg];
                            if ((col < m) & (sv < 0.9f)) { ssl += sv; scl += 1.f; }
                        }
                    }
                }
                // reduce-scatter over lq (sum for ps, min for mnv)
                const bool b4 = (lq & 4) != 0, b8 = (lq & 8) != 0;
                float a0 = b4 ? ps[0] : ps[2];
                float a1 = b4 ? ps[1] : ps[3];
                float r0 = (b4 ? ps[2] : ps[0]) + __shfl_xor(a0, 4, 64);
                float r1 = (b4 ? ps[3] : ps[1]) + __shfl_xor(a1, 4, 64);
                float a2 = b8 ? r0 : r1;
                float stot = (b8 ? r1 : r0) + __shfl_xor(a2, 8, 64);
                stot += __shfl_xor(stot, 1, 64);
                stot += __shfl_xor(stot, 2, 64);

                float m0 = b4 ? mnv[0] : mnv[2];
                float m1 = b4 ? mnv[1] : mnv[3];
                float q0 = fminf(b4 ? mnv[2] : mnv[0], __shfl_xor(m0, 4, 64));
                float q1 = fminf(b4 ? mnv[3] : mnv[1], __shfl_xor(m1, 4, 64));
                float m2 = b8 ? q0 : q1;
                float mtot = fminf(b8 ? q1 : q0, __shfl_xor(m2, 8, 64));
                mtot = fminf(mtot, __shfl_xor(mtot, 1, 64));
                mtot = fminf(mtot, __shfl_xor(mtot, 2, 64));

                if ((lq & 3) == 0) {        // one writer per (wx,row)
                    const int rr = quad * 4 + (b4 ? 2 : 0) + (b8 ? 1 : 0);
                    const int row_loc = wy * 64 + tr * 16 + rr;
                    posS[wx * 128 + row_loc] = stot;
                    posM[wx * 128 + row_loc] = mtot;
                }
            }
            if (glast) {
                #pragma unroll
                for (int o = 1; o < 16; o <<= 1) {
                    ssl += __shfl_xor(ssl, o, 64);
                    scl += __shfl_xor(scl, o, 64);
                }
                if (lq == 0 && scl > 0.f) {
                    atomicAdd(&last4[0], ssl);
                    atomicAdd(&last4[1], scl);
                }
            }
            __syncthreads();                // combine area complete

            if (tid < rleft) {              // merge wx halves, single writer
                const float stot = posS[tid] + posS[128 + tid];
                const float mtot = fminf(posM[tid], posM[128 + tid]);
                const int i = list[s0 + rbase + tid];
                if (ct == 0) { pos_sum[i] = stot; pos_min[i] = mtot; }
                else {
                    pos_sum[i] += stot;
                    pos_min[i] = fminf(pos_min[i], mtot);
                }
            }
        }
    }
}

// ---------------- kernel C: finalize (32 blocks) + exact-path cleanup ------
__global__ __launch_bounds__(256) void finalize_kernel(
    const ushort* __restrict__ xb, const int* __restrict__ t,
    const float* __restrict__ pos_min, const float* __restrict__ pos_sum,
    const float* __restrict__ part, const float* __restrict__ last4,
    float* __restrict__ out, int n)
{
    const int tid = threadIdx.x;
    const int base = blockIdx.x * 256;
    const int i = base + tid;
    const float pm = pos_min[i];
    const bool flag = (pm > 0.6f);   // pth would exceed 0.1 (incl. pm=+inf)

    __shared__ int fl[256];
    __shared__ int nfl, lastflag;
    __shared__ float corr[256];
    __shared__ float xi2[D];
    __shared__ float red[3][4];
    __shared__ float lastst[2];
    if (tid == 0) { nfl = 0; lastflag = 0; }
    __syncthreads();
    if (flag) { int q = atomicAdd(&nfl, 1); fl[q] = tid; }
    __syncthreads();
    const int m = nfl;

    for (int e = 0; e < m; ++e) {    // rare: exact recompute of flagged rows
        const int lr_ = fl[e];
        const int ri = base + lr_;
        if (tid < D)
            xi2[tid] = __uint_as_float(((unsigned)xb[(size_t)ri * D + tid]) << 16);
        __syncthreads();
        const float pth = fmaxf(0.1f, pos_min[ri] - 0.5f);
        const int lab = t[ri];
        float S = 0.f, ss = 0.f, cnt = 0.f;
        for (int j = tid; j < n; j += 256) {
            if (t[j] == lab) continue;
            float d = 0.f;
            const ushort* xr = xb + (size_t)j * D;
            for (int q = 0; q < D; ++q)
                d += __uint_as_float(((unsigned)xr[q]) << 16) * xi2[q];
            if (d > pth) {
                S += __expf(fmaf(d, d, fmaf(49.8f, d, -24.99f)));
                ss += d; cnt += 1.f;
            }
        }
        const int lane = tid & 63, wv = tid >> 6;
        S = waveSum(S); ss = waveSum(ss); cnt = waveSum(cnt);
        if (lane == 0) { red[0][wv] = S; red[1][wv] = ss; red[2][wv] = cnt; }
        __syncthreads();
        if (tid == 0) {
            corr[lr_] = red[0][0] + red[0][1] + red[0][2] + red[0][3];
            if (ri == n - 1) {
                lastst[0] = red[1][0] + red[1][1] + red[1][2] + red[1][3];
                lastst[1] = red[2][0] + red[2][1] + red[2][2] + red[2][3];
                lastflag = 1;
            }
        }
        __syncthreads();
    }

    float s;
    if (flag) {
        s = corr[tid];
    } else {
        s = 0.f;
        #pragma unroll
        for (int sl = 0; sl < 8; ++sl) s += part[(size_t)sl * n + i];
    }
    float l = 0.f, nno = 0.f;
    if (s > 0.f)       // has_neg <=> any exp term (each > 0 in fp32)
        l = 0.5f * log1pf(pos_sum[i]) + 0.02f * log1pf(s);
    else
        nno = 1.f;
    const int lane = tid & 63, wv = tid >> 6;
    l = waveSum(l); nno = waveSum(nno);
    __syncthreads();                  // red[] reuse safety
    if (lane == 0) { red[0][wv] = l; red[1][wv] = nno; }
    __syncthreads();
    if (tid == 0) {
        float L = red[0][0] + red[0][1] + red[0][2] + red[0][3];
        float P = red[1][0] + red[1][1] + red[1][2] + red[1][3];
        atomicAdd(&out[0], L / (float)n);
        atomicAdd(&out[1], P / (float)n);
    }
    if (i == n - 1) {                 // block owning the last row writes stats
        out[2] = last4[0] / fmaxf(last4[1], 1.f);
        float a = lastflag ? lastst[0] : last4[2];
        float b2 = lastflag ? lastst[1] : last4[3];
        out[3] = a / fmaxf(b2, 1.f);
    }
}

// ---------------- launch ----------------
extern "C" void kernel_launch(void* const* d_in, const int* in_sizes, int n_in,
                              void* d_out, int out_size, void* d_ws, size_t ws_size,
                              hipStream_t stream) {
    const float* x = (const float*)d_in[0];
    const int*   t = (const int*)d_in[1];
    const int n = in_sizes[1];   // 8192

    float* ws      = (float*)d_ws;
    float* pos_min = ws;                       // [n]
    float* pos_sum = ws + n;                   // [n]
    float* last4   = ws + 2 * n;               // [4]   (zeroed by prep)
    float* part    = ws + 2 * n + 4;           // [8*n] (zeroed by prep)
    int*   offs    = (int*)(ws + 10 * n + 4);             // [NL+1]
    int*   list    = (int*)(ws + 10 * n + 4 + NL + 1);    // [n]
    size_t xb_off  = ((size_t)(11 * n + 4 + NL + 1) + 3) & ~(size_t)3;
    ushort* xb     = (ushort*)(ws + xb_off);              // [n*128] bf16, 16B aligned

    const int total8 = n * D / 8;
    const int nconv = (total8 + 1023) / 1024;
    const int nzero = (8 * n + 4095) / 4096;
    prep_kernel<<<nconv + 1 + nzero, 1024, 0, stream>>>(
        x, xb, total8, t, offs, list, part, last4, (float*)d_out, n, nconv);

    const int nb = n / 128;                    // 64
    const int ntri = nb * (nb + 1) / 2;        // 2080
    fused_kernel<<<POSB + ntri, 256, 0, stream>>>(
        xb, t, offs, list, pos_min, pos_sum, part, last4, n);

    finalize_kernel<<<n / 256, 256, 0, stream>>>(xb, t, pos_min, pos_sum,
                                                 part, last4, (float*)d_out, n);
}